// Round 22
// baseline (897.115 us; speedup 1.0000x reference)
//
#include <hip/hip_runtime.h>
#include <math.h>

// ws layout (exactly 160 MiB):
//   Ph: _Float16 [9][64][1024][64]  (72 MiB)  "hi" fp16 split of proj
//   Pl: _Float16 [9][64][1024][64]  (72 MiB)  "lo" fp16 split of proj
//   attn region (16 MiB): first used as xh/xl fp16 pre-split of x, then attn f32
// w order: 0=q,1=k,2=v,3=q_left,4=k_left,5=q_right,6=k_right,7=q_local,8=k_local
// layout per matrix: [bh][t][d]  EXCEPT w==2 (v): fragment-ordered for PV.

typedef _Float16 half8 __attribute__((ext_vector_type(8)));
typedef _Float16 half4v __attribute__((ext_vector_type(4)));
typedef _Float16 half2v __attribute__((ext_vector_type(2)));
typedef float f32x4 __attribute__((ext_vector_type(4)));

#define MFMA16(A, B, C) __builtin_amdgcn_mfma_f32_16x16x32_f16(A, B, C, 0, 0, 0)

// LDS (f32 words): sRed 1280 + lvB 8704 (8 waves*[16][136] fp16) + sChunk 2560
// sOut [128][65] (8320 words) overlaps lvB (dead after PV; guarded by barrier)
#define SMEM_ATTN ((1280 + 8704 + 2560) * 4)

static __device__ __forceinline__ unsigned packhl(_Float16 a, _Float16 b) {
  half2v v; v[0] = a; v[1] = b;
  return __builtin_bit_cast(unsigned, v);
}

// ---------------- fp32 -> fp16 h/l pre-split (vectorized) ----------------
__global__ __launch_bounds__(256)
void split_hl(const float* __restrict__ x, _Float16* __restrict__ xh,
              _Float16* __restrict__ xl) {
  const int i = blockIdx.x * 256 + threadIdx.x;
  const float4 v = ((const float4*)x)[i];
  half4v h, l;
  const float* f = (const float*)&v;
#pragma unroll
  for (int e = 0; e < 4; ++e) {
    h[e] = (_Float16)f[e];
    l[e] = (_Float16)(f[e] - (float)h[e]);
  }
  ((half4v*)xh)[i] = h;
  ((half4v*)xl)[i] = l;
}

// ---------------- split-fp16 MFMA GEMM: C = A * B^T + bias ----------------
// MODE 0: A fp32, C fp32 out.  MODE 1: A pre-split fp16 (Axh/Axl), proj scatter.
// 1D grid, XCD-chunked: each XCD owns 4 contiguous m-blocks across all NB n-blocks
// (A panels stay L2-resident per XCD; B streams from L3).
template<int MODE>
__global__ __launch_bounds__(256, 2)
void gemm_mfma(const float* __restrict__ A, const float* __restrict__ B,
               const float* __restrict__ bias, float* __restrict__ C,
               _Float16* __restrict__ Ph, _Float16* __restrict__ Pl,
               const _Float16* __restrict__ Axh, const _Float16* __restrict__ Axl,
               int M, int N, int K, int NB) {
  __shared__ _Float16 Ah[128 * 64], Al[128 * 64], Bh[128 * 64], Bl[128 * 64];
  const int tid = threadIdx.x;
  const int nbx = blockIdx.x;
  const int xcd = nbx & 7, loc = nbx >> 3;
  const int m0 = (xcd * 4 + loc / NB) * 128;
  const int n0 = (loc % NB) * 128;
  const int wave = tid >> 6, lane = tid & 63;
  const int g2 = lane >> 4, c = lane & 15;
  const int wm = (wave >> 1) * 64, wn = (wave & 1) * 64;

  const int srow = tid >> 1;
  const int shalf = (tid & 1) * 32;
  const int swz = (srow & 7) << 3;
  const float* ap = A + (size_t)(m0 + srow) * K + shalf;
  const float* bp = B + (size_t)(n0 + srow) * K + shalf;
  const _Float16* aph = Axh + (size_t)(m0 + srow) * K + shalf;
  const _Float16* apl = Axl + (size_t)(m0 + srow) * K + shalf;

  f32x4 acc[4][4];
#pragma unroll
  for (int i = 0; i < 4; ++i)
#pragma unroll
    for (int j = 0; j < 4; ++j) acc[i][j] = (f32x4){0.f, 0.f, 0.f, 0.f};

  for (int k0 = 0; k0 < K; k0 += 64) {
    float4 av[8], bv[8];
    half8 ah8[4], al8[4];
    if (MODE == 1) {
#pragma unroll
      for (int u = 0; u < 4; ++u) {
        ah8[u] = *(const half8*)(aph + k0 + u * 8);
        al8[u] = *(const half8*)(apl + k0 + u * 8);
      }
    } else {
#pragma unroll
      for (int u = 0; u < 8; ++u) av[u] = *(const float4*)(ap + k0 + u * 4);
    }
#pragma unroll
    for (int u = 0; u < 8; ++u) bv[u] = *(const float4*)(bp + k0 + u * 4);
    __syncthreads();
    if (MODE == 1) {
#pragma unroll
      for (int u = 0; u < 4; ++u) {
        const int cc = (shalf + u * 8) ^ swz;
        *(half8*)&Ah[srow * 64 + cc] = ah8[u];
        *(half8*)&Al[srow * 64 + cc] = al8[u];
      }
    }
#pragma unroll
    for (int u = 0; u < 8; ++u) {
      const int cc = (shalf + u * 4) ^ swz;
      half4v h4b, l4b;
      const float* fb = (const float*)&bv[u];
#pragma unroll
      for (int e = 0; e < 4; ++e) {
        _Float16 hb = (_Float16)fb[e];
        h4b[e] = hb; l4b[e] = (_Float16)(fb[e] - (float)hb);
      }
      if (MODE == 0) {
        half4v h4a, l4a;
        const float* fa = (const float*)&av[u];
#pragma unroll
        for (int e = 0; e < 4; ++e) {
          _Float16 ha = (_Float16)fa[e];
          h4a[e] = ha; l4a[e] = (_Float16)(fa[e] - (float)ha);
        }
        *(half4v*)&Ah[srow * 64 + cc] = h4a;
        *(half4v*)&Al[srow * 64 + cc] = l4a;
      }
      *(half4v*)&Bh[srow * 64 + cc] = h4b;
      *(half4v*)&Bl[srow * 64 + cc] = l4b;
    }
    __syncthreads();
#pragma unroll
    for (int ks = 0; ks < 2; ++ks) {
      const int kb = ks * 32 + 8 * g2;
      half8 a_h[4], a_l[4];
#pragma unroll
      for (int i = 0; i < 4; ++i) {
        const int row = wm + i * 16 + c;
        const int cc = kb ^ ((row & 7) << 3);
        a_h[i] = *(const half8*)&Ah[row * 64 + cc];
        a_l[i] = *(const half8*)&Al[row * 64 + cc];
      }
#pragma unroll
      for (int j = 0; j < 4; ++j) {
        const int rowb = wn + j * 16 + c;
        const int cc = kb ^ ((rowb & 7) << 3);
        const half8 b_h = *(const half8*)&Bh[rowb * 64 + cc];
        const half8 b_l = *(const half8*)&Bl[rowb * 64 + cc];
#pragma unroll
        for (int i = 0; i < 4; ++i) {
          acc[i][j] = MFMA16(a_h[i], b_h, acc[i][j]);
          acc[i][j] = MFMA16(a_h[i], b_l, acc[i][j]);
          acc[i][j] = MFMA16(a_l[i], b_h, acc[i][j]);
        }
      }
    }
  }

#pragma unroll
  for (int j = 0; j < 4; ++j) {
    const int nj = n0 + wn + j * 16 + c;
    const float bz = bias[nj];
    if (MODE == 0) {
#pragma unroll
      for (int i = 0; i < 4; ++i)
#pragma unroll
        for (int q = 0; q < 4; ++q) {
          const int mi = m0 + wm + i * 16 + 4 * g2 + q;
          C[(size_t)mi * N + nj] = acc[i][j][q] + bz;
        }
    } else {
      const int w = nj >> 10, hh = (nj >> 6) & 15, d = nj & 63;
      const float scale = (w == 0 || w == 7) ? 0.125f : 1.0f;
#pragma unroll
      for (int i = 0; i < 4; ++i)
#pragma unroll
        for (int q = 0; q < 4; ++q) {
          const int mi = m0 + wm + i * 16 + 4 * g2 + q;
          const int t = mi >> 2, b2 = mi & 3;
          const size_t bb = ((size_t)w * 64 + (b2 * 16 + hh)) * 65536;
          size_t idx;
          if (w == 2) {
            // fragment-ordered V: chunk=s>>5, block=chunk*4+(d>>4),
            // within: [(s>>3)&3][d&15][s&7]
            idx = bb + (size_t)((t >> 5) * 4 + (d >> 4)) * 512
                     + ((t >> 3) & 3) * 128 + (d & 15) * 8 + (t & 7);
          } else {
            idx = bb + (size_t)t * 64 + d;
          }
          const float v = (acc[i][j][q] + bz) * scale;
          const _Float16 h16 = (_Float16)v;
          Ph[idx] = h16;
          Pl[idx] = (_Float16)(v - (float)h16);
        }
    }
  }
}

// -------- fused attention: one score array in regs; LEFT/mask/local live in LDS fp16 --------
// grid 4096 (XCD-chunked), block 512 (8 waves), LDS 49 KB -> 2 WG/CU
// Per wave: lane c = t-row (t0+c); s = sbase + 16*m + 4*g2 + q  (m=tile 0..7)
__global__ __launch_bounds__(512, 4)
void attn_mfma(const _Float16* __restrict__ Ph, const _Float16* __restrict__ Pl,
               float* __restrict__ attnOut) {
  extern __shared__ float smem[];
  float* sRed = smem;                                   // [4][16 rows x stride 20]
  _Float16* lvB = (_Float16*)(smem + 1280);             // [8][16][136] fp16
  _Float16* sChunk = (_Float16*)(smem + 1280 + 8704);   // [8][16][40] fp16
  float* sOut = smem + 1280;                            // overlaps lvB (post-PV)
  const int flat = blockIdx.x;
  const int nf = (flat & 7) * 512 + (flat >> 3);        // XCD-chunked
  const int bh = nf >> 6;
  const int t0 = (nf & 63) << 4;
  const int tid = threadIdx.x;
  const int wave = tid >> 6, lane = tid & 63;
  const int g2 = lane >> 4, c = lane & 15;
  const int sbase = wave << 7;                          // 128-s slice
  _Float16* lw = lvB + wave * 2176 + c * 136;           // this lane's row

  auto mbase = [&](int w) { return ((size_t)w * 64 + bh) * 65536; };

  struct QF { half8 h0, h1, l0, l1; };
  auto loadQ = [&](int wq) {
    QF f;
    const _Float16* qh = Ph + mbase(wq) + (size_t)(t0 + c) * 64 + 8 * g2;
    const _Float16* ql = Pl + mbase(wq) + (size_t)(t0 + c) * 64 + 8 * g2;
    f.h0 = *(const half8*)qh; f.h1 = *(const half8*)(qh + 32);
    f.l0 = *(const half8*)ql; f.l1 = *(const half8*)(ql + 32);
    return f;
  };
  // transposed score tile, register-lean: one K-frag live at a time
  auto stileT = [&](const QF& f, const _Float16* kbh, const _Float16* kbl, int tp) {
    const int s0 = sbase + tp * 16;
    const _Float16* kh = kbh + (size_t)(s0 + c) * 64 + 8 * g2;
    const _Float16* kl = kbl + (size_t)(s0 + c) * 64 + 8 * g2;
    f32x4 a = {0.f, 0.f, 0.f, 0.f};
    half8 t = *(const half8*)kh;          // ah0
    a = MFMA16(t, f.h0, a);
    a = MFMA16(t, f.l0, a);
    t = *(const half8*)(kh + 32);         // ah1
    a = MFMA16(t, f.h1, a);
    a = MFMA16(t, f.l1, a);
    t = *(const half8*)kl;                // al0
    a = MFMA16(t, f.h0, a);
    t = *(const half8*)(kl + 32);         // al1
    a = MFMA16(t, f.h1, a);
    return a;
  };

  auto put = [&](int slot, float val) {
    if (lane < 16) sRed[slot * 320 + c * 20 + wave] = val;
  };
  auto sum_pref = [&](int slot, float& pref) {
    const float* p = sRed + slot * 320 + c * 20;
    float a[8];
    *(f32x4*)&a[0] = *(const f32x4*)p;
    *(f32x4*)&a[4] = *(const f32x4*)(p + 4);
    float S = 0.f;
    pref = 0.f;
#pragma unroll
    for (int w = 0; w < 8; ++w) {
      S += a[w];
      if (w < wave) pref += a[w];
    }
    return S;
  };
  auto sum_only = [&](int slot) {
    const float* p = sRed + slot * 320 + c * 20;
    float a[8];
    *(f32x4*)&a[0] = *(const f32x4*)p;
    *(f32x4*)&a[4] = *(const f32x4*)(p + 4);
    float S = 0.f;
#pragma unroll
    for (int w = 0; w < 8; ++w) S += a[w];
    return S;
  };
  auto scan_s = [&](f32x4* v) {
    float carry = 0.f;
#pragma unroll
    for (int m = 0; m < 8; ++m) {
      v[m][1] += v[m][0];
      v[m][2] += v[m][1];
      v[m][3] += v[m][2];
      const float B = v[m][3];
      float sc = B;
      const float u1 = __shfl_up(sc, 16, 64);
      if (g2 >= 1) sc += u1;
      const float u2 = __shfl_up(sc, 32, 64);
      if (g2 >= 2) sc += u2;
      const float e = sc - B + carry;
      v[m][0] += e; v[m][1] += e; v[m][2] += e; v[m][3] += e;
      carry += __shfl(sc, 48 + c, 64);
    }
    return carry;
  };
  auto rowsum = [&](const f32x4* v) {
    float s = 0.f;
#pragma unroll
    for (int m = 0; m < 8; ++m) s += (v[m][0] + v[m][1]) + (v[m][2] + v[m][3]);
    s += __shfl_xor(s, 16, 64);
    s += __shfl_xor(s, 32, 64);
    return s;
  };
  auto scorephase = [&](int wq, int wk, f32x4* v) {
    const QF f = loadQ(wq);
    const _Float16* kbh = Ph + mbase(wk);
    const _Float16* kbl = Pl + mbase(wk);
#pragma unroll
    for (int m = 0; m < 8; ++m) {
      const f32x4 a = stileT(f, kbh, kbl, m);
#pragma unroll
      for (int q = 0; q < 4; ++q) v[m][q] = __expf(a[q]);
    }
  };

  f32x4 rv[8];

  // ===== LEFT: exp, cumsum -> store raw inclusive cumsum to lvB (fp16); regs die =====
  {
    f32x4 lv[8];
    scorephase(3, 4, lv);
    put(0, scan_s(lv));
#pragma unroll
    for (int m = 0; m < 8; ++m) {
      const int sc = 16 * m + 4 * g2;
      *(unsigned*)&lw[sc] = packhl((_Float16)lv[m][0], (_Float16)lv[m][1]);
      *(unsigned*)&lw[sc + 2] = packhl((_Float16)lv[m][2], (_Float16)lv[m][3]);
    }
  }
  // ===== RIGHT -> rv (exp, cumsum) =====
  scorephase(5, 6, rv);
  put(1, scan_s(rv));
  __syncthreads();                              // B1
  // ===== mask: stream per tile; af from LDS, bf from rv; write mask to lvB =====
  {
    float prefL, prefR;
    const float SL = sum_pref(0, prefL);
    const float SR = sum_pref(1, prefR);
    const float invSL = 1.f / SL, invSR = 1.f / SR;
    const float bL = prefL * invSL, bR = prefR * invSR;
#pragma unroll
    for (int m = 0; m < 8; ++m)
#pragma unroll
      for (int q = 0; q < 4; ++q) rv[m][q] = (rv[m][q] + prefR) * invSR;
#pragma unroll
    for (int m = 7; m >= 0; --m) {              // descending: reads stay ahead of writes
      const int sc = 16 * m + 4 * g2;
      const half4v a4 = *(const half4v*)&lw[sc];
      float afn[4];
#pragma unroll
      for (int q = 0; q < 4; ++q) afn[q] = ((float)a4[q] + prefL) * invSL;
      const int rsc = (sc == 0) ? 0 : sc - 1;
      const float prevr = (float)lw[rsc];
      const float afb = (sc == 0) ? bL : (prevr + prefL) * invSL;
      const float bU = __shfl_up(rv[m][3], 16, 64);
      const float bM = (m > 0) ? __shfl(rv[m - 1][3], 48 + c, 64) : bR;
      const float b0 = (g2 == 0) ? bM : bU;
      float mk[4];
      mk[0] = afn[0] * (1.f - b0)       + (1.f - afb)    * rv[m][0];
      mk[1] = afn[1] * (1.f - rv[m][0]) + (1.f - afn[0]) * rv[m][1];
      mk[2] = afn[2] * (1.f - rv[m][1]) + (1.f - afn[1]) * rv[m][2];
      mk[3] = afn[3] * (1.f - rv[m][2]) + (1.f - afn[2]) * rv[m][3];
      *(unsigned*)&lw[sc] = packhl((_Float16)mk[0], (_Float16)mk[1]);
      *(unsigned*)&lw[sc + 2] = packhl((_Float16)mk[2], (_Float16)mk[3]);
    }
  }
  // ===== LOCAL: stream per tile; exp*mask -> lvB fp16 (sum the rounded values) =====
  {
    const QF f = loadQ(7);
    const _Float16* k8h = Ph + mbase(8);
    const _Float16* k8l = Pl + mbase(8);
    float s = 0.f;
#pragma unroll
    for (int m = 0; m < 8; ++m) {
      const f32x4 a = stileT(f, k8h, k8l, m);
      const int sc = 16 * m + 4 * g2;
      const half4v m4 = *(const half4v*)&lw[sc];
      _Float16 vh[4];
#pragma unroll
      for (int q = 0; q < 4; ++q) {
        vh[q] = (_Float16)(__expf(a[q]) * (float)m4[q]);
        s += (float)vh[q];
      }
      *(unsigned*)&lw[sc] = packhl(vh[0], vh[1]);
      *(unsigned*)&lw[sc + 2] = packhl(vh[2], vh[3]);
    }
    s += __shfl_xor(s, 16, 64);
    s += __shfl_xor(s, 32, 64);
    put(2, s);
  }
  // ===== GLOBAL -> rv (exp) =====
  scorephase(0, 1, rv);
  put(3, rowsum(rv));
  __syncthreads();                              // B2
  // ===== PV with fused pack: P = local*scO + rv*scG (fp16, h-only) =====
  f32x4 cacc[4];
#pragma unroll
  for (int dt = 0; dt < 4; ++dt) cacc[dt] = (f32x4){0.f, 0.f, 0.f, 0.f};
  {
    const float scO = 0.5f / sum_only(2);
    const float scG = 0.5f / sum_only(3);
    _Float16* chw = sChunk + wave * (16 * 40);       // [16][40]
    const _Float16* vbh = Ph + mbase(2);
    const _Float16* vbl = Pl + mbase(2);
#pragma unroll
    for (int kk = 0; kk < 4; ++kk) {
#pragma unroll
      for (int mlo = 0; mlo < 2; ++mlo) {
        const int m = 2 * kk + mlo;
        const int sc = 16 * m + 4 * g2;
        const half4v l4 = *(const half4v*)&lw[sc];
        const int off = c * 40 + 16 * mlo + 4 * g2;
        *(unsigned*)&chw[off] = packhl(
            (_Float16)((float)l4[0] * scO + rv[m][0] * scG),
            (_Float16)((float)l4[1] * scO + rv[m][1] * scG));
        *(unsigned*)&chw[off + 2] = packhl(
            (_Float16)((float)l4[2] * scO + rv[m][2] * scG),
            (_Float16)((float)l4[3] * scO + rv[m][3] * scG));
      }
      const half8 pah = *(const half8*)&chw[c * 40 + 8 * g2];
#pragma unroll
      for (int dt = 0; dt < 4; ++dt) {
        const size_t vo = (size_t)(((wave * 4 + kk) * 4 + dt) << 9) + (g2 << 7) + (c << 3);
        const half8 bh8 = *(const half8*)(vbh + vo);
        const half8 bl8 = *(const half8*)(vbl + vo);
        cacc[dt] = MFMA16(pah, bh8, cacc[dt]);
        cacc[dt] = MFMA16(pah, bl8, cacc[dt]);
      }
    }
  }
  __syncthreads();                  // B3a: all lvB reads done before sOut overwrite
#pragma unroll
  for (int dt = 0; dt < 4; ++dt)
#pragma unroll
    for (int q = 0; q < 4; ++q)
      sOut[(wave * 16 + 4 * g2 + q) * 65 + dt * 16 + c] = cacc[dt][q];
  __syncthreads();                  // B3
  {
    const int b2 = bh >> 4, hh = bh & 15;
#pragma unroll
    for (int o = tid; o < 1024; o += 512) {
      const int r = o >> 6, d = o & 63;
      float a = 0.f;
#pragma unroll
      for (int w = 0; w < 8; ++w) a += sOut[(w * 16 + r) * 65 + d];
      attnOut[((size_t)(t0 + r) * 4 + b2) * 1024 + hh * 64 + d] = a;
    }
  }
}

extern "C" void kernel_launch(void* const* d_in, const int* in_sizes, int n_in,
                              void* d_out, int out_size, void* d_ws, size_t ws_size,
                              hipStream_t stream) {
  const float* x     = (const float*)d_in[0];
  const float* w_in  = (const float*)d_in[1];
  const float* b_in  = (const float*)d_in[2];
  const float* w_out = (const float*)d_in[3];
  const float* b_out = (const float*)d_in[4];

  const size_t NP = (size_t)9 * 64 * 1024 * 64;
  _Float16* Ph = (_Float16*)d_ws;
  _Float16* Pl = Ph + NP;
  float* attn = (float*)(Pl + NP);            // 16 MiB region
  _Float16* xh = (_Float16*)attn;             // transient: fp16 h split of x
  _Float16* xl = xh + (size_t)4096 * 1024;    // transient: fp16 l split of x

  (void)hipFuncSetAttribute((const void*)attn_mfma,
                            hipFuncAttributeMaxDynamicSharedMemorySize,
                            SMEM_ATTN);

  // pre-split x -> fp16 h/l (4096*1024 elems, float4-vectorized)
  split_hl<<<4096, 256, 0, stream>>>(x, xh, xl);
  // proj = x @ w_in^T + b_in -> fp16 h/l split, head-major; v fragment-ordered
  // grid 2304 = 8 XCD chunks x (4 m-blocks x 72 n-blocks)
  gemm_mfma<1><<<2304, 256, 0, stream>>>(nullptr, w_in, b_in, nullptr, Ph, Pl, xh, xl, 4096, 9216, 1024, 72);
  // fused attention (overwrites xh/xl region with attn output)
  attn_mfma<<<4096, 512, SMEM_ATTN, stream>>>(Ph, Pl, attn);
  // out = attn @ w_out^T + b_out; grid 256 = 8 x (4 m x 8 n)
  gemm_mfma<0><<<256, 256, 0, stream>>>(attn, w_out, b_out, (float*)d_out, nullptr, nullptr, nullptr, nullptr, 4096, 1024, 1024, 8);
}

// Round 23
// 866.681 us; speedup vs baseline: 1.0351x; 1.0351x over previous
//
#include <hip/hip_runtime.h>
#include <math.h>

// ws layout (exactly 160 MiB):
//   Ph: _Float16 [9][64][1024][64]  (72 MiB)  "hi" fp16 split of proj
//   Pl: _Float16 [9][64][1024][64]  (72 MiB)  "lo" fp16 split of proj
//   attn region (16 MiB): first used as xh/xl fp16 pre-split of x, then attn f32
// w order: 0=q,1=k,2=v,3=q_left,4=k_left,5=q_right,6=k_right,7=q_local,8=k_local
// layout per matrix: [bh][t][d]  EXCEPT w==2 (v): fragment-ordered for PV.

typedef _Float16 half8 __attribute__((ext_vector_type(8)));
typedef _Float16 half4v __attribute__((ext_vector_type(4)));
typedef _Float16 half2v __attribute__((ext_vector_type(2)));
typedef float f32x4 __attribute__((ext_vector_type(4)));

#define MFMA16(A, B, C) __builtin_amdgcn_mfma_f32_16x16x32_f16(A, B, C, 0, 0, 0)

// LDS (f32 words): sRed 1280 + lvB 8704 (8 waves*[16][136] fp16) + sChunk 2560
// sOut [128][65] (8320 words) overlaps lvB (dead after PV; guarded by barrier)
#define SMEM_ATTN ((1280 + 8704 + 2560) * 4)

static __device__ __forceinline__ unsigned packhl(_Float16 a, _Float16 b) {
  half2v v; v[0] = a; v[1] = b;
  return __builtin_bit_cast(unsigned, v);
}

// ---------------- fp32 -> fp16 h/l pre-split (vectorized) ----------------
__global__ __launch_bounds__(256)
void split_hl(const float* __restrict__ x, _Float16* __restrict__ xh,
              _Float16* __restrict__ xl) {
  const int i = blockIdx.x * 256 + threadIdx.x;
  const float4 v = ((const float4*)x)[i];
  half4v h, l;
  const float* f = (const float*)&v;
#pragma unroll
  for (int e = 0; e < 4; ++e) {
    h[e] = (_Float16)f[e];
    l[e] = (_Float16)(f[e] - (float)h[e]);
  }
  ((half4v*)xh)[i] = h;
  ((half4v*)xl)[i] = l;
}

// ---------------- split-fp16 MFMA GEMM: C = A * B^T + bias ----------------
// MODE 0: A fp32, C fp32 out.  MODE 1: A pre-split fp16 (Axh/Axl), proj scatter.
template<int MODE>
__global__ __launch_bounds__(256, 2)
void gemm_mfma(const float* __restrict__ A, const float* __restrict__ B,
               const float* __restrict__ bias, float* __restrict__ C,
               _Float16* __restrict__ Ph, _Float16* __restrict__ Pl,
               const _Float16* __restrict__ Axh, const _Float16* __restrict__ Axl,
               int M, int N, int K) {
  __shared__ _Float16 Ah[128 * 64], Al[128 * 64], Bh[128 * 64], Bl[128 * 64];
  const int tid = threadIdx.x;
  const int m0 = blockIdx.x * 128, n0 = blockIdx.y * 128;
  const int wave = tid >> 6, lane = tid & 63;
  const int g2 = lane >> 4, c = lane & 15;
  const int wm = (wave >> 1) * 64, wn = (wave & 1) * 64;

  const int srow = tid >> 1;
  const int shalf = (tid & 1) * 32;
  const int swz = (srow & 7) << 3;
  const float* ap = A + (size_t)(m0 + srow) * K + shalf;
  const float* bp = B + (size_t)(n0 + srow) * K + shalf;
  const _Float16* aph = Axh + (size_t)(m0 + srow) * K + shalf;
  const _Float16* apl = Axl + (size_t)(m0 + srow) * K + shalf;

  f32x4 acc[4][4];
#pragma unroll
  for (int i = 0; i < 4; ++i)
#pragma unroll
    for (int j = 0; j < 4; ++j) acc[i][j] = (f32x4){0.f, 0.f, 0.f, 0.f};

  for (int k0 = 0; k0 < K; k0 += 64) {
    float4 av[8], bv[8];
    half8 ah8[4], al8[4];
    if (MODE == 1) {
#pragma unroll
      for (int u = 0; u < 4; ++u) {
        ah8[u] = *(const half8*)(aph + k0 + u * 8);
        al8[u] = *(const half8*)(apl + k0 + u * 8);
      }
    } else {
#pragma unroll
      for (int u = 0; u < 8; ++u) av[u] = *(const float4*)(ap + k0 + u * 4);
    }
#pragma unroll
    for (int u = 0; u < 8; ++u) bv[u] = *(const float4*)(bp + k0 + u * 4);
    __syncthreads();
    if (MODE == 1) {
#pragma unroll
      for (int u = 0; u < 4; ++u) {
        const int cc = (shalf + u * 8) ^ swz;
        *(half8*)&Ah[srow * 64 + cc] = ah8[u];
        *(half8*)&Al[srow * 64 + cc] = al8[u];
      }
    }
#pragma unroll
    for (int u = 0; u < 8; ++u) {
      const int cc = (shalf + u * 4) ^ swz;
      half4v h4b, l4b;
      const float* fb = (const float*)&bv[u];
#pragma unroll
      for (int e = 0; e < 4; ++e) {
        _Float16 hb = (_Float16)fb[e];
        h4b[e] = hb; l4b[e] = (_Float16)(fb[e] - (float)hb);
      }
      if (MODE == 0) {
        half4v h4a, l4a;
        const float* fa = (const float*)&av[u];
#pragma unroll
        for (int e = 0; e < 4; ++e) {
          _Float16 ha = (_Float16)fa[e];
          h4a[e] = ha; l4a[e] = (_Float16)(fa[e] - (float)ha);
        }
        *(half4v*)&Ah[srow * 64 + cc] = h4a;
        *(half4v*)&Al[srow * 64 + cc] = l4a;
      }
      *(half4v*)&Bh[srow * 64 + cc] = h4b;
      *(half4v*)&Bl[srow * 64 + cc] = l4b;
    }
    __syncthreads();
#pragma unroll
    for (int ks = 0; ks < 2; ++ks) {
      const int kb = ks * 32 + 8 * g2;
      half8 a_h[4], a_l[4];
#pragma unroll
      for (int i = 0; i < 4; ++i) {
        const int row = wm + i * 16 + c;
        const int cc = kb ^ ((row & 7) << 3);
        a_h[i] = *(const half8*)&Ah[row * 64 + cc];
        a_l[i] = *(const half8*)&Al[row * 64 + cc];
      }
#pragma unroll
      for (int j = 0; j < 4; ++j) {
        const int rowb = wn + j * 16 + c;
        const int cc = kb ^ ((rowb & 7) << 3);
        const half8 b_h = *(const half8*)&Bh[rowb * 64 + cc];
        const half8 b_l = *(const half8*)&Bl[rowb * 64 + cc];
#pragma unroll
        for (int i = 0; i < 4; ++i) {
          acc[i][j] = MFMA16(a_h[i], b_h, acc[i][j]);
          acc[i][j] = MFMA16(a_h[i], b_l, acc[i][j]);
          acc[i][j] = MFMA16(a_l[i], b_h, acc[i][j]);
        }
      }
    }
  }

#pragma unroll
  for (int j = 0; j < 4; ++j) {
    const int nj = n0 + wn + j * 16 + c;
    const float bz = bias[nj];
    if (MODE == 0) {
#pragma unroll
      for (int i = 0; i < 4; ++i)
#pragma unroll
        for (int q = 0; q < 4; ++q) {
          const int mi = m0 + wm + i * 16 + 4 * g2 + q;
          C[(size_t)mi * N + nj] = acc[i][j][q] + bz;
        }
    } else {
      const int w = nj >> 10, hh = (nj >> 6) & 15, d = nj & 63;
      const float scale = (w == 0 || w == 7) ? 0.125f : 1.0f;
#pragma unroll
      for (int i = 0; i < 4; ++i)
#pragma unroll
        for (int q = 0; q < 4; ++q) {
          const int mi = m0 + wm + i * 16 + 4 * g2 + q;
          const int t = mi >> 2, b2 = mi & 3;
          const size_t bb = ((size_t)w * 64 + (b2 * 16 + hh)) * 65536;
          size_t idx;
          if (w == 2) {
            // fragment-ordered V: chunk=s>>5, block=chunk*4+(d>>4),
            // within: [(s>>3)&3][d&15][s&7]
            idx = bb + (size_t)((t >> 5) * 4 + (d >> 4)) * 512
                     + ((t >> 3) & 3) * 128 + (d & 15) * 8 + (t & 7);
          } else {
            idx = bb + (size_t)t * 64 + d;
          }
          const float v = (acc[i][j][q] + bz) * scale;
          const _Float16 h16 = (_Float16)v;
          Ph[idx] = h16;
          Pl[idx] = (_Float16)(v - (float)h16);
        }
    }
  }
}

// -------- fused attention: one score array in regs; LEFT/mask/local live in LDS fp16 --------
// grid 4096 (XCD-chunked), block 512 (8 waves), LDS 49 KB -> 2 WG/CU
// Per wave: lane c = t-row (t0+c); s = sbase + 16*m + 4*g2 + q  (m=tile 0..7)
__global__ __launch_bounds__(512, 4)
void attn_mfma(const _Float16* __restrict__ Ph, const _Float16* __restrict__ Pl,
               float* __restrict__ attnOut) {
  extern __shared__ float smem[];
  float* sRed = smem;                                   // [4][16 rows x stride 20]
  _Float16* lvB = (_Float16*)(smem + 1280);             // [8][16][136] fp16
  _Float16* sChunk = (_Float16*)(smem + 1280 + 8704);   // [8][16][40] fp16
  float* sOut = smem + 1280;                            // overlaps lvB (post-PV)
  const int flat = blockIdx.x;
  const int nf = (flat & 7) * 512 + (flat >> 3);        // XCD-chunked
  const int bh = nf >> 6;
  const int t0 = (nf & 63) << 4;
  const int tid = threadIdx.x;
  const int wave = tid >> 6, lane = tid & 63;
  const int g2 = lane >> 4, c = lane & 15;
  const int sbase = wave << 7;                          // 128-s slice
  _Float16* lw = lvB + wave * 2176 + c * 136;           // this lane's row

  auto mbase = [&](int w) { return ((size_t)w * 64 + bh) * 65536; };

  struct QF { half8 h0, h1, l0, l1; };
  auto loadQ = [&](int wq) {
    QF f;
    const _Float16* qh = Ph + mbase(wq) + (size_t)(t0 + c) * 64 + 8 * g2;
    const _Float16* ql = Pl + mbase(wq) + (size_t)(t0 + c) * 64 + 8 * g2;
    f.h0 = *(const half8*)qh; f.h1 = *(const half8*)(qh + 32);
    f.l0 = *(const half8*)ql; f.l1 = *(const half8*)(ql + 32);
    return f;
  };
  // transposed score tile, register-lean: one K-frag live at a time
  auto stileT = [&](const QF& f, const _Float16* kbh, const _Float16* kbl, int tp) {
    const int s0 = sbase + tp * 16;
    const _Float16* kh = kbh + (size_t)(s0 + c) * 64 + 8 * g2;
    const _Float16* kl = kbl + (size_t)(s0 + c) * 64 + 8 * g2;
    f32x4 a = {0.f, 0.f, 0.f, 0.f};
    half8 t = *(const half8*)kh;          // ah0
    a = MFMA16(t, f.h0, a);
    a = MFMA16(t, f.l0, a);
    t = *(const half8*)(kh + 32);         // ah1
    a = MFMA16(t, f.h1, a);
    a = MFMA16(t, f.l1, a);
    t = *(const half8*)kl;                // al0
    a = MFMA16(t, f.h0, a);
    t = *(const half8*)(kl + 32);         // al1
    a = MFMA16(t, f.h1, a);
    return a;
  };

  auto put = [&](int slot, float val) {
    if (lane < 16) sRed[slot * 320 + c * 20 + wave] = val;
  };
  auto sum_pref = [&](int slot, float& pref) {
    const float* p = sRed + slot * 320 + c * 20;
    float a[8];
    *(f32x4*)&a[0] = *(const f32x4*)p;
    *(f32x4*)&a[4] = *(const f32x4*)(p + 4);
    float S = 0.f;
    pref = 0.f;
#pragma unroll
    for (int w = 0; w < 8; ++w) {
      S += a[w];
      if (w < wave) pref += a[w];
    }
    return S;
  };
  auto sum_only = [&](int slot) {
    const float* p = sRed + slot * 320 + c * 20;
    float a[8];
    *(f32x4*)&a[0] = *(const f32x4*)p;
    *(f32x4*)&a[4] = *(const f32x4*)(p + 4);
    float S = 0.f;
#pragma unroll
    for (int w = 0; w < 8; ++w) S += a[w];
    return S;
  };
  auto scan_s = [&](f32x4* v) {
    float carry = 0.f;
#pragma unroll
    for (int m = 0; m < 8; ++m) {
      v[m][1] += v[m][0];
      v[m][2] += v[m][1];
      v[m][3] += v[m][2];
      const float B = v[m][3];
      float sc = B;
      const float u1 = __shfl_up(sc, 16, 64);
      if (g2 >= 1) sc += u1;
      const float u2 = __shfl_up(sc, 32, 64);
      if (g2 >= 2) sc += u2;
      const float e = sc - B + carry;
      v[m][0] += e; v[m][1] += e; v[m][2] += e; v[m][3] += e;
      carry += __shfl(sc, 48 + c, 64);
    }
    return carry;
  };
  auto rowsum = [&](const f32x4* v) {
    float s = 0.f;
#pragma unroll
    for (int m = 0; m < 8; ++m) s += (v[m][0] + v[m][1]) + (v[m][2] + v[m][3]);
    s += __shfl_xor(s, 16, 64);
    s += __shfl_xor(s, 32, 64);
    return s;
  };
  auto scorephase = [&](int wq, int wk, f32x4* v) {
    const QF f = loadQ(wq);
    const _Float16* kbh = Ph + mbase(wk);
    const _Float16* kbl = Pl + mbase(wk);
#pragma unroll
    for (int m = 0; m < 8; ++m) {
      const f32x4 a = stileT(f, kbh, kbl, m);
#pragma unroll
      for (int q = 0; q < 4; ++q) v[m][q] = __expf(a[q]);
    }
  };

  f32x4 rv[8];

  // ===== LEFT: exp, cumsum -> store raw inclusive cumsum to lvB (fp16); regs die =====
  {
    f32x4 lv[8];
    scorephase(3, 4, lv);
    put(0, scan_s(lv));
#pragma unroll
    for (int m = 0; m < 8; ++m) {
      const int sc = 16 * m + 4 * g2;
      *(unsigned*)&lw[sc] = packhl((_Float16)lv[m][0], (_Float16)lv[m][1]);
      *(unsigned*)&lw[sc + 2] = packhl((_Float16)lv[m][2], (_Float16)lv[m][3]);
    }
  }
  // ===== RIGHT -> rv (exp, cumsum) =====
  scorephase(5, 6, rv);
  put(1, scan_s(rv));
  __syncthreads();                              // B1
  // ===== mask: stream per tile; af from LDS, bf from rv; write mask to lvB =====
  {
    float prefL, prefR;
    const float SL = sum_pref(0, prefL);
    const float SR = sum_pref(1, prefR);
    const float invSL = 1.f / SL, invSR = 1.f / SR;
    const float bL = prefL * invSL, bR = prefR * invSR;
#pragma unroll
    for (int m = 0; m < 8; ++m)
#pragma unroll
      for (int q = 0; q < 4; ++q) rv[m][q] = (rv[m][q] + prefR) * invSR;
#pragma unroll
    for (int m = 7; m >= 0; --m) {              // descending: reads stay ahead of writes
      const int sc = 16 * m + 4 * g2;
      const half4v a4 = *(const half4v*)&lw[sc];
      float afn[4];
#pragma unroll
      for (int q = 0; q < 4; ++q) afn[q] = ((float)a4[q] + prefL) * invSL;
      const int rsc = (sc == 0) ? 0 : sc - 1;
      const float prevr = (float)lw[rsc];
      const float afb = (sc == 0) ? bL : (prevr + prefL) * invSL;
      const float bU = __shfl_up(rv[m][3], 16, 64);
      const float bM = (m > 0) ? __shfl(rv[m - 1][3], 48 + c, 64) : bR;
      const float b0 = (g2 == 0) ? bM : bU;
      float mk[4];
      mk[0] = afn[0] * (1.f - b0)       + (1.f - afb)    * rv[m][0];
      mk[1] = afn[1] * (1.f - rv[m][0]) + (1.f - afn[0]) * rv[m][1];
      mk[2] = afn[2] * (1.f - rv[m][1]) + (1.f - afn[1]) * rv[m][2];
      mk[3] = afn[3] * (1.f - rv[m][2]) + (1.f - afn[2]) * rv[m][3];
      *(unsigned*)&lw[sc] = packhl((_Float16)mk[0], (_Float16)mk[1]);
      *(unsigned*)&lw[sc + 2] = packhl((_Float16)mk[2], (_Float16)mk[3]);
    }
  }
  // ===== LOCAL: stream per tile; exp*mask -> lvB fp16 (sum the rounded values) =====
  {
    const QF f = loadQ(7);
    const _Float16* k8h = Ph + mbase(8);
    const _Float16* k8l = Pl + mbase(8);
    float s = 0.f;
#pragma unroll
    for (int m = 0; m < 8; ++m) {
      const f32x4 a = stileT(f, k8h, k8l, m);
      const int sc = 16 * m + 4 * g2;
      const half4v m4 = *(const half4v*)&lw[sc];
      _Float16 vh[4];
#pragma unroll
      for (int q = 0; q < 4; ++q) {
        vh[q] = (_Float16)(__expf(a[q]) * (float)m4[q]);
        s += (float)vh[q];
      }
      *(unsigned*)&lw[sc] = packhl(vh[0], vh[1]);
      *(unsigned*)&lw[sc + 2] = packhl(vh[2], vh[3]);
    }
    s += __shfl_xor(s, 16, 64);
    s += __shfl_xor(s, 32, 64);
    put(2, s);
  }
  // ===== GLOBAL -> rv (exp) =====
  scorephase(0, 1, rv);
  put(3, rowsum(rv));
  __syncthreads();                              // B2
  // ===== PV with fused pack: P = local*scO + rv*scG (fp16, h-only) =====
  f32x4 cacc[4];
#pragma unroll
  for (int dt = 0; dt < 4; ++dt) cacc[dt] = (f32x4){0.f, 0.f, 0.f, 0.f};
  {
    const float scO = 0.5f / sum_only(2);
    const float scG = 0.5f / sum_only(3);
    _Float16* chw = sChunk + wave * (16 * 40);       // [16][40]
    const _Float16* vbh = Ph + mbase(2);
    const _Float16* vbl = Pl + mbase(2);
#pragma unroll
    for (int kk = 0; kk < 4; ++kk) {
#pragma unroll
      for (int mlo = 0; mlo < 2; ++mlo) {
        const int m = 2 * kk + mlo;
        const int sc = 16 * m + 4 * g2;
        const half4v l4 = *(const half4v*)&lw[sc];
        const int off = c * 40 + 16 * mlo + 4 * g2;
        *(unsigned*)&chw[off] = packhl(
            (_Float16)((float)l4[0] * scO + rv[m][0] * scG),
            (_Float16)((float)l4[1] * scO + rv[m][1] * scG));
        *(unsigned*)&chw[off + 2] = packhl(
            (_Float16)((float)l4[2] * scO + rv[m][2] * scG),
            (_Float16)((float)l4[3] * scO + rv[m][3] * scG));
      }
      const half8 pah = *(const half8*)&chw[c * 40 + 8 * g2];
#pragma unroll
      for (int dt = 0; dt < 4; ++dt) {
        const size_t vo = (size_t)(((wave * 4 + kk) * 4 + dt) << 9) + (g2 << 7) + (c << 3);
        const half8 bh8 = *(const half8*)(vbh + vo);
        const half8 bl8 = *(const half8*)(vbl + vo);
        cacc[dt] = MFMA16(pah, bh8, cacc[dt]);
        cacc[dt] = MFMA16(pah, bl8, cacc[dt]);
      }
    }
  }
  __syncthreads();                  // B3a: all lvB reads done before sOut overwrite
#pragma unroll
  for (int dt = 0; dt < 4; ++dt)
#pragma unroll
    for (int q = 0; q < 4; ++q)
      sOut[(wave * 16 + 4 * g2 + q) * 65 + dt * 16 + c] = cacc[dt][q];
  __syncthreads();                  // B3
  {
    const int b2 = bh >> 4, hh = bh & 15;
#pragma unroll
    for (int o = tid; o < 1024; o += 512) {
      const int r = o >> 6, d = o & 63;
      float a = 0.f;
#pragma unroll
      for (int w = 0; w < 8; ++w) a += sOut[(w * 16 + r) * 65 + d];
      attnOut[((size_t)(t0 + r) * 4 + b2) * 1024 + hh * 64 + d] = a;
    }
  }
}

extern "C" void kernel_launch(void* const* d_in, const int* in_sizes, int n_in,
                              void* d_out, int out_size, void* d_ws, size_t ws_size,
                              hipStream_t stream) {
  const float* x     = (const float*)d_in[0];
  const float* w_in  = (const float*)d_in[1];
  const float* b_in  = (const float*)d_in[2];
  const float* w_out = (const float*)d_in[3];
  const float* b_out = (const float*)d_in[4];

  const size_t NP = (size_t)9 * 64 * 1024 * 64;
  _Float16* Ph = (_Float16*)d_ws;
  _Float16* Pl = Ph + NP;
  float* attn = (float*)(Pl + NP);            // 16 MiB region
  _Float16* xh = (_Float16*)attn;             // transient: fp16 h split of x
  _Float16* xl = xh + (size_t)4096 * 1024;    // transient: fp16 l split of x

  (void)hipFuncSetAttribute((const void*)attn_mfma,
                            hipFuncAttributeMaxDynamicSharedMemorySize,
                            SMEM_ATTN);

  // pre-split x -> fp16 h/l (4096*1024 elems, float4-vectorized)
  split_hl<<<4096, 256, 0, stream>>>(x, xh, xl);
  // proj = x @ w_in^T + b_in -> fp16 h/l split, head-major; v fragment-ordered
  gemm_mfma<1><<<dim3(32, 72), 256, 0, stream>>>(nullptr, w_in, b_in, nullptr, Ph, Pl, xh, xl, 4096, 9216, 1024);
  // fused attention (overwrites xh/xl region with attn output)
  attn_mfma<<<4096, 512, SMEM_ATTN, stream>>>(Ph, Pl, attn);
  // out = attn @ w_out^T + b_out
  gemm_mfma<0><<<dim3(32, 8), 256, 0, stream>>>(attn, w_out, b_out, (float*)d_out, nullptr, nullptr, nullptr, nullptr, 4096, 1024, 1024);
}